// Round 1
// baseline (373.582 us; speedup 1.0000x reference)
//
#include <hip/hip_runtime.h>
#include <cstdint>

#define DIMC   1024
#define NHEADS 16
#define HD     64
#define BATCH  2
#define SEQ    2048
#define MROWS  (BATCH*SEQ)   // 4096
#define QKSCALE 0.125f       // 64^-0.5

typedef __bf16 bf16x8 __attribute__((ext_vector_type(8)));
typedef float  f32x4  __attribute__((ext_vector_type(4)));

#define AST 88   // LDS row stride in bf16 elems: 176B -> 16B aligned, 2-way bank aliasing only

__device__ __forceinline__ unsigned short f2bf(float f) {
    union { float f; unsigned int u; } v; v.f = f;
    unsigned int u = v.u;
    u += 0x7fffu + ((u >> 16) & 1u);   // round-to-nearest-even
    return (unsigned short)(u >> 16);
}

// ---------------------------------------------------------------------------
// QKV projection: C[m][n] = sum_k x[m][k] * W[n][k]   (x fp32, W fp32, out bf16)
// 128x128 block tile, BK=64, 4 waves each computing 64x64 via 4x4 16x16x32 MFMAs.
// blockIdx.z selects Wq/Wk/Wv -> q/k/v.
// ---------------------------------------------------------------------------
__global__ __launch_bounds__(256) void gemm_qkv(
    const float* __restrict__ x,
    const float* __restrict__ Wq, const float* __restrict__ Wk, const float* __restrict__ Wv,
    unsigned short* __restrict__ qo, unsigned short* __restrict__ ko, unsigned short* __restrict__ vo)
{
    __shared__ unsigned short As[128 * AST];
    __shared__ unsigned short Bs[128 * AST];

    const int t  = threadIdx.x;
    const int n0 = blockIdx.x * 128;
    const int m0 = blockIdx.y * 128;
    const int z  = blockIdx.z;
    const float* W = (z == 0) ? Wq : (z == 1) ? Wk : Wv;
    unsigned short* Out = (z == 0) ? qo : (z == 1) ? ko : vo;

    const int w = t >> 6, l = t & 63, quad = l >> 4, lr = l & 15;
    const int wr = w >> 1, wc = w & 1;

    f32x4 acc[4][4];
#pragma unroll
    for (int mt = 0; mt < 4; ++mt)
#pragma unroll
        for (int nt = 0; nt < 4; ++nt)
#pragma unroll
            for (int r = 0; r < 4; ++r) acc[mt][nt][r] = 0.f;

    for (int kt = 0; kt < DIMC; kt += 64) {
        __syncthreads();
#pragma unroll
        for (int i = 0; i < 8; ++i) {
            int flat = t + i * 256;          // 2048 float4-segments per tile
            int row = flat >> 4;             // 16 segs of 4 per 64-wide row
            int seg = flat & 15;
            float4 a = *(const float4*)(x + (size_t)(m0 + row) * DIMC + kt + seg * 4);
            ushort4 pa; pa.x = f2bf(a.x); pa.y = f2bf(a.y); pa.z = f2bf(a.z); pa.w = f2bf(a.w);
            *(ushort4*)&As[row * AST + seg * 4] = pa;
            float4 b = *(const float4*)(W + (size_t)(n0 + row) * DIMC + kt + seg * 4);
            ushort4 pb; pb.x = f2bf(b.x); pb.y = f2bf(b.y); pb.z = f2bf(b.z); pb.w = f2bf(b.w);
            *(ushort4*)&Bs[row * AST + seg * 4] = pb;
        }
        __syncthreads();
#pragma unroll
        for (int kk = 0; kk < 2; ++kk) {
            bf16x8 af[4], bfr[4];
#pragma unroll
            for (int mt = 0; mt < 4; ++mt)
                af[mt] = *(const bf16x8*)&As[(wr * 64 + mt * 16 + lr) * AST + kk * 32 + quad * 8];
#pragma unroll
            for (int nt = 0; nt < 4; ++nt)
                bfr[nt] = *(const bf16x8*)&Bs[(wc * 64 + nt * 16 + lr) * AST + kk * 32 + quad * 8];
#pragma unroll
            for (int mt = 0; mt < 4; ++mt)
#pragma unroll
                for (int nt = 0; nt < 4; ++nt)
                    acc[mt][nt] = __builtin_amdgcn_mfma_f32_16x16x32_bf16(af[mt], bfr[nt], acc[mt][nt], 0, 0, 0);
        }
    }

#pragma unroll
    for (int mt = 0; mt < 4; ++mt)
#pragma unroll
        for (int nt = 0; nt < 4; ++nt)
#pragma unroll
            for (int r = 0; r < 4; ++r) {
                int row = m0 + wr * 64 + mt * 16 + quad * 4 + r;   // D row = quad*4+reg
                int col = n0 + wc * 64 + nt * 16 + lr;             // D col = lane&15
                Out[(size_t)row * DIMC + col] = f2bf(acc[mt][nt][r]);
            }
}

// ---------------------------------------------------------------------------
// Output projection: out[m][n] = sum_k O[m][k] * Wp[n][k] + bp[n]  (O bf16, fp32 out)
// ---------------------------------------------------------------------------
__global__ __launch_bounds__(256) void gemm_out(
    const unsigned short* __restrict__ A, const float* __restrict__ Wp,
    const float* __restrict__ bias, float* __restrict__ out)
{
    __shared__ unsigned short As[128 * AST];
    __shared__ unsigned short Bs[128 * AST];

    const int t  = threadIdx.x;
    const int n0 = blockIdx.x * 128;
    const int m0 = blockIdx.y * 128;
    const int w = t >> 6, l = t & 63, quad = l >> 4, lr = l & 15;
    const int wr = w >> 1, wc = w & 1;

    f32x4 acc[4][4];
#pragma unroll
    for (int mt = 0; mt < 4; ++mt)
#pragma unroll
        for (int nt = 0; nt < 4; ++nt)
#pragma unroll
            for (int r = 0; r < 4; ++r) acc[mt][nt][r] = 0.f;

    for (int kt = 0; kt < DIMC; kt += 64) {
        __syncthreads();
#pragma unroll
        for (int i = 0; i < 8; ++i) {
            int flat = t + i * 256;
            int row = flat >> 4;
            int seg = flat & 15;
            ushort4 a = *(const ushort4*)(A + (size_t)(m0 + row) * DIMC + kt + seg * 4);
            *(ushort4*)&As[row * AST + seg * 4] = a;
            float4 b = *(const float4*)(Wp + (size_t)(n0 + row) * DIMC + kt + seg * 4);
            ushort4 pb; pb.x = f2bf(b.x); pb.y = f2bf(b.y); pb.z = f2bf(b.z); pb.w = f2bf(b.w);
            *(ushort4*)&Bs[row * AST + seg * 4] = pb;
        }
        __syncthreads();
#pragma unroll
        for (int kk = 0; kk < 2; ++kk) {
            bf16x8 af[4], bfr[4];
#pragma unroll
            for (int mt = 0; mt < 4; ++mt)
                af[mt] = *(const bf16x8*)&As[(wr * 64 + mt * 16 + lr) * AST + kk * 32 + quad * 8];
#pragma unroll
            for (int nt = 0; nt < 4; ++nt)
                bfr[nt] = *(const bf16x8*)&Bs[(wc * 64 + nt * 16 + lr) * AST + kk * 32 + quad * 8];
#pragma unroll
            for (int mt = 0; mt < 4; ++mt)
#pragma unroll
                for (int nt = 0; nt < 4; ++nt)
                    acc[mt][nt] = __builtin_amdgcn_mfma_f32_16x16x32_bf16(af[mt], bfr[nt], acc[mt][nt], 0, 0, 0);
        }
    }

#pragma unroll
    for (int mt = 0; mt < 4; ++mt)
#pragma unroll
        for (int nt = 0; nt < 4; ++nt)
#pragma unroll
            for (int r = 0; r < 4; ++r) {
                int row = m0 + wr * 64 + mt * 16 + quad * 4 + r;
                int col = n0 + wc * 64 + nt * 16 + lr;
                out[(size_t)row * DIMC + col] = acc[mt][nt][r] + bias[col];
            }
}

// ---------------------------------------------------------------------------
// Flash attention: one block per (b, h, 64-row Q tile); 4 waves x 16 Q-rows.
// q/k/v layout: [b][n][h*64+d] bf16 (row stride 1024).
// ---------------------------------------------------------------------------
__global__ __launch_bounds__(256) void attn_kernel(
    const unsigned short* __restrict__ qg, const unsigned short* __restrict__ kg,
    const unsigned short* __restrict__ vg, unsigned short* __restrict__ og)
{
    __shared__ unsigned short Ks[64 * AST];       // K tile [kv][d]
    __shared__ unsigned short Vt[64 * AST];       // V tile transposed [d][kv]
    __shared__ unsigned short Ps[4 * 16 * AST];   // per-wave P [qrow][kv]

    const int t  = threadIdx.x;
    const int qt = blockIdx.x, h = blockIdx.y, b = blockIdx.z;
    const int w = t >> 6, l = t & 63, quad = l >> 4, lr = l & 15;

    // Q fragments (A-operand): lane holds Q[m=lr][k=quad*8+j], 2 k-steps of 32
    const size_t qoff = ((size_t)(b * SEQ + qt * 64 + w * 16 + lr)) * DIMC + h * HD;
    const bf16x8 qf0 = *(const bf16x8*)(qg + qoff + 0  + quad * 8);
    const bf16x8 qf1 = *(const bf16x8*)(qg + qoff + 32 + quad * 8);

    float m_i[4], l_i[4];
    f32x4 o_acc[4];
#pragma unroll
    for (int r = 0; r < 4; ++r) { m_i[r] = -1e30f; l_i[r] = 0.f; }
#pragma unroll
    for (int ct = 0; ct < 4; ++ct)
#pragma unroll
        for (int r = 0; r < 4; ++r) o_acc[ct][r] = 0.f;

    for (int kt = 0; kt < SEQ / 64; ++kt) {
        __syncthreads();   // previous iter's frag reads done before overwrite
#pragma unroll
        for (int i = 0; i < 2; ++i) {
            int flat = t + i * 256;        // 512 8-elem segments per 64x64 tile
            int row = flat >> 3, seg = flat & 7;
            size_t goff = ((size_t)(b * SEQ + kt * 64 + row)) * DIMC + h * HD + seg * 8;
            *(uint4*)&Ks[row * AST + seg * 8] = *(const uint4*)(kg + goff);
            unsigned short vv[8];
            *(uint4*)vv = *(const uint4*)(vg + goff);
#pragma unroll
            for (int e = 0; e < 8; ++e)
                Vt[(seg * 8 + e) * AST + row] = vv[e];   // transpose: [d][kv]
        }
        __syncthreads();

        // S = Q*K^T (16 q-rows x 64 kv) in C-layout: row=quad*4+r, col=nt*16+lr
        f32x4 s[4];
#pragma unroll
        for (int nt = 0; nt < 4; ++nt)
#pragma unroll
            for (int r = 0; r < 4; ++r) s[nt][r] = 0.f;
#pragma unroll
        for (int kk = 0; kk < 2; ++kk) {
            const bf16x8 qf = kk ? qf1 : qf0;
#pragma unroll
            for (int nt = 0; nt < 4; ++nt) {
                bf16x8 kf = *(const bf16x8*)&Ks[(nt * 16 + lr) * AST + kk * 32 + quad * 8];
                s[nt] = __builtin_amdgcn_mfma_f32_16x16x32_bf16(qf, kf, s[nt], 0, 0, 0);
            }
        }

        // online softmax (per r = per q-row; reduce over 16 lanes of the quad)
        float tmax[4] = { -1e30f, -1e30f, -1e30f, -1e30f };
#pragma unroll
        for (int nt = 0; nt < 4; ++nt)
#pragma unroll
            for (int r = 0; r < 4; ++r) {
                s[nt][r] *= QKSCALE;
                tmax[r] = fmaxf(tmax[r], s[nt][r]);
            }
#pragma unroll
        for (int off = 1; off <= 8; off <<= 1)
#pragma unroll
            for (int r = 0; r < 4; ++r)
                tmax[r] = fmaxf(tmax[r], __shfl_xor(tmax[r], off));

        float alpha[4], rsum[4] = { 0.f, 0.f, 0.f, 0.f };
#pragma unroll
        for (int r = 0; r < 4; ++r) {
            float mn = fmaxf(m_i[r], tmax[r]);
            alpha[r] = __expf(m_i[r] - mn);
            m_i[r] = mn;
        }
#pragma unroll
        for (int nt = 0; nt < 4; ++nt)
#pragma unroll
            for (int r = 0; r < 4; ++r) {
                float p = __expf(s[nt][r] - m_i[r]);
                s[nt][r] = p;
                rsum[r] += p;
            }
#pragma unroll
        for (int off = 1; off <= 8; off <<= 1)
#pragma unroll
            for (int r = 0; r < 4; ++r)
                rsum[r] += __shfl_xor(rsum[r], off);
#pragma unroll
        for (int r = 0; r < 4; ++r) l_i[r] = l_i[r] * alpha[r] + rsum[r];
#pragma unroll
        for (int ct = 0; ct < 4; ++ct)
#pragma unroll
            for (int r = 0; r < 4; ++r) o_acc[ct][r] *= alpha[r];

        // P: C-layout regs -> LDS -> A-operand layout
#pragma unroll
        for (int nt = 0; nt < 4; ++nt)
#pragma unroll
            for (int r = 0; r < 4; ++r)
                Ps[(w * 16 + quad * 4 + r) * AST + nt * 16 + lr] = f2bf(s[nt][r]);
        __syncthreads();

        // O += P*V
#pragma unroll
        for (int kk = 0; kk < 2; ++kk) {
            bf16x8 pf = *(const bf16x8*)&Ps[(w * 16 + lr) * AST + kk * 32 + quad * 8];
#pragma unroll
            for (int ct = 0; ct < 4; ++ct) {
                bf16x8 vf = *(const bf16x8*)&Vt[(ct * 16 + lr) * AST + kk * 32 + quad * 8];
                o_acc[ct] = __builtin_amdgcn_mfma_f32_16x16x32_bf16(pf, vf, o_acc[ct], 0, 0, 0);
            }
        }
    }

    float inv[4];
#pragma unroll
    for (int r = 0; r < 4; ++r) inv[r] = 1.0f / l_i[r];
#pragma unroll
    for (int ct = 0; ct < 4; ++ct)
#pragma unroll
        for (int r = 0; r < 4; ++r) {
            int qrow = qt * 64 + w * 16 + quad * 4 + r;
            og[((size_t)(b * SEQ + qrow)) * DIMC + h * HD + ct * 16 + lr] =
                f2bf(o_acc[ct][r] * inv[r]);
        }
}

// ---------------------------------------------------------------------------
extern "C" void kernel_launch(void* const* d_in, const int* in_sizes, int n_in,
                              void* d_out, int out_size, void* d_ws, size_t ws_size,
                              hipStream_t stream)
{
    const float* x  = (const float*)d_in[0];
    const float* Wq = (const float*)d_in[1];
    const float* Wk = (const float*)d_in[2];
    const float* Wv = (const float*)d_in[3];
    const float* Wp = (const float*)d_in[4];
    const float* bp = (const float*)d_in[5];
    float* out = (float*)d_out;

    const size_t SZ = (size_t)MROWS * DIMC;   // 4M elems
    unsigned short* q = (unsigned short*)d_ws;
    unsigned short* k = q + SZ;
    unsigned short* v = k + SZ;
    unsigned short* o = v + SZ;

    gemm_qkv<<<dim3(DIMC / 128, MROWS / 128, 3), 256, 0, stream>>>(x, Wq, Wk, Wv, q, k, v);
    attn_kernel<<<dim3(SEQ / 64, NHEADS, BATCH), 256, 0, stream>>>(q, k, v, o);
    gemm_out<<<dim3(DIMC / 128, MROWS / 128, 1), 256, 0, stream>>>(o, Wp, bp, out);
}